// Round 9
// baseline (97.842 us; speedup 1.0000x reference)
//
#include <hip/hip_runtime.h>
#include <stdint.h>

// CorrelationLayer via MFMA Gram tiles.
// out[j*7+i, h, w] = sum_c x[c,h,w] * y[c,h+j-3,w+i-3], zero-padded.
//
// R9: block = 256 thr / 4 waves = (2 h-rows x 32-px slab); wave-unit =
// (h0+dh, 16-px tile ww). LDS y tile: rows h0-3..h0+4 (8) x cols ws_blk-4..
// ws_blk+35 (40) x k-chunk 32 (pad 40) bf16, k-contiguous per col (80 B).
// Staging unit = (row, kb, col-pair): 8x float2 loads (8 k-planes) ->
// 8 pkbf -> 2x b128 LDS writes. cb is even so float2 never straddles the
// image edge -> per-unit uniform validity; OOB rows/cols written as zeros.
// Verified math carried from R6/R7: A/B frag lane {m|n}=l&15, k=(l>>4)*8+e;
// C/D col=lane&15, row=(lane>>4)*4+reg; extraction slab 16x34, i=g / g+4.
// R8 lesson: af[] must only ever be indexed by compile-time constants
// (runtime-indexed ext_vector array -> scratch; WRITE_SIZE 38->93 MB).
// Grid 192 hp x 16 slabs = 3072; XCD k owns hp [24k,24k+24), slab-fastest
// so one hp's 16 blocks share its 8 y-rows (2 MB, L2-resident).

typedef __attribute__((ext_vector_type(8))) short short8;
typedef __attribute__((ext_vector_type(4))) float floatx4;

constexpr int C = 128;
constexpr int H = 384;
constexpr int W = 512;
constexpr int HW = H * W;

constexpr int NROW = 8;
constexpr int NCOL = 40;             // LDS col 0 = abs ws_blk - 4
constexpr int KP   = 40;             // bf16 per col (32 k + 8 pad) = 80 B
constexpr int ROWB = NCOL * KP * 2;  // 3200 B per row

__device__ __forceinline__ uint32_t pkbf(float a, float b) {
  uint32_t ua = (__float_as_uint(a) + 0x8000u) >> 16;
  uint32_t ub = (__float_as_uint(b) + 0x8000u) & 0xffff0000u;
  return ua | ub;
}

union S8U { uint32_t u[4]; short8 s; };

template <bool SAFE>
__device__ __forceinline__ void stage_chunk(const float* __restrict__ y,
                                            uint16_t* __restrict__ ys,
                                            int kc, int h0, int ws_blk,
                                            int tid) {
  // units: 8 rows x 4 kb x 20 col-pairs = 640
#pragma unroll
  for (int it = 0; it < 3; ++it) {
    const int u = it * 256 + tid;
    if (u < 640) {
      const int c2  = u % 20;
      const int kb  = (u / 20) & 3;
      const int row = u / 80;
      const int r_abs = h0 - 3 + row;
      const int cb    = ws_blk - 4 + 2 * c2;   // even -> no edge straddle
      bool val = true;
      int r = r_abs, cc = cb;
      if (!SAFE) {
        val = (r_abs >= 0) & (r_abs < H) & (cb >= 0) & (cb <= W - 2);
        r  = r_abs < 0 ? 0 : (r_abs >= H ? H - 1 : r_abs);
        cc = cb < 0 ? 0 : (cb > W - 2 ? W - 2 : cb);
      }
      const float* src = y + (size_t)(kc * 32 + kb * 8) * HW +
                         (size_t)r * W + cc;
      float2 f[8];
#pragma unroll
      for (int e = 0; e < 8; ++e)
        f[e] = *reinterpret_cast<const float2*>(src + (size_t)e * HW);
      uint4 v0, v1;
      v0.x = pkbf(f[0].x, f[1].x); v0.y = pkbf(f[2].x, f[3].x);
      v0.z = pkbf(f[4].x, f[5].x); v0.w = pkbf(f[6].x, f[7].x);
      v1.x = pkbf(f[0].y, f[1].y); v1.y = pkbf(f[2].y, f[3].y);
      v1.z = pkbf(f[4].y, f[5].y); v1.w = pkbf(f[6].y, f[7].y);
      if (!SAFE) {
        if (!val) { v0 = make_uint4(0, 0, 0, 0); v1 = make_uint4(0, 0, 0, 0); }
      }
      uint16_t* d0 = &ys[((row * NCOL) + 2 * c2) * KP + kb * 8];
      *reinterpret_cast<uint4*>(d0)      = v0;
      *reinterpret_cast<uint4*>(d0 + KP) = v1;
    }
  }
}

__global__ __launch_bounds__(256, 4)
void corr_mfma(const float* __restrict__ x, const float* __restrict__ y,
               float* __restrict__ out) {
  __shared__ uint16_t ys[NROW * NCOL * KP];   // 25600 B

  const int bid  = blockIdx.x;
  const int xcd  = bid & 7;
  const int idx  = bid >> 3;                  // 0..383
  const int slab = idx & 15;
  const int hp   = xcd * 24 + (idx >> 4);     // h-pair index 0..191
  const int h0     = hp * 2;
  const int ws_blk = slab * 32;
  const int tid  = threadIdx.x;
  const int wv   = tid >> 6;
  const int lane = tid & 63;
  const int m  = lane & 15;
  const int g  = lane >> 4;
  const int dh = wv >> 1;                     // 0..1
  const int ww = wv & 1;                      // 0..1
  const int h  = h0 + dh;
  const int ws = ws_blk + ww * 16;

  const bool safe = (hp >= 2) & (hp <= 189) & (slab >= 1) & (slab <= 14);

  floatx4 acc[7][2];
#pragma unroll
  for (int j = 0; j < 7; ++j) {
    acc[j][0] = (floatx4){0.f, 0.f, 0.f, 0.f};
    acc[j][1] = (floatx4){0.f, 0.f, 0.f, 0.f};
  }

  // ---- A fragments preload: af[kc], A[m][k] = x[k][h][ws+m], k=g*8+e ----
  short8 af[4];
  {
    const float* xb = x + (size_t)(g * 8) * HW + (size_t)h * W + (ws + m);
#pragma unroll
    for (int kc = 0; kc < 4; ++kc) {
      float f[8];
#pragma unroll
      for (int e = 0; e < 8; ++e) f[e] = xb[(size_t)(kc * 32 + e) * HW];
      S8U s;
      s.u[0] = pkbf(f[0], f[1]);
      s.u[1] = pkbf(f[2], f[3]);
      s.u[2] = pkbf(f[4], f[5]);
      s.u[3] = pkbf(f[6], f[7]);
      af[kc] = s.s;
    }
  }

  // per-lane b128 read byte-offsets within a row slab
  const int col0 = ww * 16 + m + 1;           // abs ws-3+m
  int col1 = col0 + 16;                       // tile1; clamp unused lanes
  if (col1 > NCOL - 1) col1 = NCOL - 1;
  const int fb0 = col0 * (KP * 2) + g * 16;
  const int fb1 = col1 * (KP * 2) + g * 16;

#pragma unroll
  for (int kc = 0; kc < 4; ++kc) {            // forced unroll: af[kc] static
    if (kc) __syncthreads();                  // protect previous chunk reads
    if (safe) stage_chunk<true >(y, ys, kc, h0, ws_blk, tid);
    else      stage_chunk<false>(y, ys, kc, h0, ws_blk, tid);
    __syncthreads();

#pragma unroll
    for (int j = 0; j < 7; ++j) {
      const uint8_t* rb =
          reinterpret_cast<const uint8_t*>(ys) + (dh + j) * ROWB;
      const short8 b0 = *reinterpret_cast<const short8*>(rb + fb0);
      const short8 b1 = *reinterpret_cast<const short8*>(rb + fb1);
      acc[j][0] = __builtin_amdgcn_mfma_f32_16x16x32_bf16(af[kc], b0, acc[j][0], 0, 0, 0);
      acc[j][1] = __builtin_amdgcn_mfma_f32_16x16x32_bf16(af[kc], b1, acc[j][1], 0, 0, 0);
    }
  }

  // ---- extraction: per-wave 16x34 f32 slab (reuses ys after barrier) ----
  __syncthreads();
  float* slabp = reinterpret_cast<float*>(ys) + wv * 544;
#pragma unroll
  for (int j = 0; j < 7; ++j) {
#pragma unroll
    for (int q = 0; q < 4; ++q) {
      slabp[(g * 4 + q) * 34 + m]      = acc[j][0][q];   // cols 0..15
      slabp[(g * 4 + q) * 34 + 16 + m] = acc[j][1][q];   // cols 16..31
    }
    const float vo0 = slabp[m * 34 + m + g];             // i = g
    const float vo1 = slabp[m * 34 + m + g + 4];         // i = g+4 (g<3)
    float* ob = out + (size_t)(j * 7 + g) * HW + (size_t)h * W + (ws + m);
    *ob = vo0;
    if (g < 3) ob[(size_t)4 * HW] = vo1;
  }
}

extern "C" void kernel_launch(void* const* d_in, const int* in_sizes, int n_in,
                              void* d_out, int out_size, void* d_ws, size_t ws_size,
                              hipStream_t stream) {
  const float* x = (const float*)d_in[0];
  const float* y = (const float*)d_in[1];
  float* out = (float*)d_out;
  corr_mfma<<<dim3(192 * 16), dim3(256), 0, stream>>>(x, y, out);
}